// Round 1
// baseline (616.870 us; speedup 1.0000x reference)
//
#include <hip/hip_runtime.h>

// Problem constants
#define BB 256
#define TT 512
#define DIN 128
#define HH 256
#define DOUT 64
#define X_ELEMS ((long)BB * 513 * DOUT)

typedef short bf16x8 __attribute__((ext_vector_type(8)));
typedef float f32x4 __attribute__((ext_vector_type(4)));
typedef _Float16 half2_t __attribute__((ext_vector_type(2)));
typedef _Float16 half8_t __attribute__((ext_vector_type(8)));

static __device__ inline short f2bf(float f) {
    unsigned u = __float_as_uint(f);
    unsigned r = (u + 0x7FFFu + ((u >> 16) & 1u)) >> 16;
    return (short)r;
}

static __device__ inline float fdot2f(half2_t a, half2_t b, float c) {
#if __has_builtin(__builtin_amdgcn_fdot2)
    return __builtin_amdgcn_fdot2(a, b, c, false);
#else
    return c + (float)a[0] * (float)b[0] + (float)a[1] * (float)b[1];
#endif
}

// butterfly-add across a lane quad via DPP quad_perm (XOR1 then XOR2).
// All 4 lanes of the quad end up with the full 4-lane sum. Pure VALU.
static __device__ inline float quad_bfly_add(float x) {
    int t = __builtin_amdgcn_mov_dpp(__float_as_int(x), 0xB1, 0xF, 0xF, true); // [1,0,3,2]
    x += __int_as_float(t);
    t = __builtin_amdgcn_mov_dpp(__float_as_int(x), 0x4E, 0xF, 0xF, true);     // [2,3,0,1]
    x += __int_as_float(t);
    return x;
}

// Block barrier that waits ONLY on LDS ops (lgkmcnt), NOT vmcnt.
// __syncthreads() forces s_waitcnt vmcnt(0) before s_barrier, which
// synchronously drains the U-prefetch global load + h global store every
// step (~600 cy stall/step at 1 wave/SIMD). Correctness here only needs
// LDS write visibility: double-buffered h + column-disjoint global
// accesses (thread owns column tid) make vmcnt drain unnecessary.
static __device__ inline void block_sync_lds() {
    __builtin_amdgcn_sched_barrier(0);
    asm volatile("s_waitcnt lgkmcnt(0)" ::: "memory");
    __builtin_amdgcn_s_barrier();
    __builtin_amdgcn_sched_barrier(0);
}

// ---------------------------------------------------------------------------
// Kernel A: U[b,t,:] = b_ih + inputs[b,t,:] @ W_u^T  (W_u = W_ih[:, 0:128])
// into h-rows 1..512 of d_out. Full-K staging, ONE barrier per block.
// grid (2048,4), block 256. Tile M64 x N64, K=128.
// ---------------------------------------------------------------------------
#define SA 136  // LDS row stride (shorts) for K=128: 272 B, 16-aligned
__global__ __launch_bounds__(256) void gemm_u(
        const float* __restrict__ inp, const float* __restrict__ W_ih,
        const float* __restrict__ b_ih, float* __restrict__ out_h) {
    __shared__ __align__(16) short lA[64 * SA];
    __shared__ __align__(16) short lB[64 * SA];
    const int tid = threadIdx.x;
    const int wave = tid >> 6, lane = tid & 63;
    const int quad = lane >> 4, l16 = lane & 15;
    const int m0 = blockIdx.x * 64;
    const int n0 = blockIdx.y * 64;
    const int sm = tid >> 2, skg = tid & 3;
    const int sn = tid & 63, bkg = tid >> 6;

    // issue ALL global loads up front, then convert+store to LDS, one barrier
    float4 a4[8], b4[8];
#pragma unroll
    for (int c = 0; c < 4; ++c) {
        const float4* ap = (const float4*)(inp + (long)(m0 + sm) * DIN + c * 32 + skg * 8);
        a4[2 * c] = ap[0]; a4[2 * c + 1] = ap[1];
        const float4* bp = (const float4*)(W_ih + (long)(n0 + sn) * 384 + c * 32 + bkg * 8);
        b4[2 * c] = bp[0]; b4[2 * c + 1] = bp[1];
    }
#pragma unroll
    for (int c = 0; c < 4; ++c) {
        bf16x8 av, bv;
        float4 x0 = a4[2 * c], x1 = a4[2 * c + 1];
        av[0] = f2bf(x0.x); av[1] = f2bf(x0.y); av[2] = f2bf(x0.z); av[3] = f2bf(x0.w);
        av[4] = f2bf(x1.x); av[5] = f2bf(x1.y); av[6] = f2bf(x1.z); av[7] = f2bf(x1.w);
        float4 y0 = b4[2 * c], y1 = b4[2 * c + 1];
        bv[0] = f2bf(y0.x); bv[1] = f2bf(y0.y); bv[2] = f2bf(y0.z); bv[3] = f2bf(y0.w);
        bv[4] = f2bf(y1.x); bv[5] = f2bf(y1.y); bv[6] = f2bf(y1.z); bv[7] = f2bf(y1.w);
        *(bf16x8*)&lA[sm * SA + c * 32 + skg * 8] = av;
        *(bf16x8*)&lB[sn * SA + c * 32 + bkg * 8] = bv;
    }
    __syncthreads();

    f32x4 acc[4];
#pragma unroll
    for (int i = 0; i < 4; i++) acc[i] = (f32x4){0.f, 0.f, 0.f, 0.f};
#pragma unroll
    for (int c = 0; c < 4; ++c) {
        bf16x8 af = *(const bf16x8*)&lA[(wave * 16 + l16) * SA + c * 32 + quad * 8];
#pragma unroll
        for (int nt = 0; nt < 4; ++nt) {
            bf16x8 bf = *(const bf16x8*)&lB[(nt * 16 + l16) * SA + c * 32 + quad * 8];
            acc[nt] = __builtin_amdgcn_mfma_f32_16x16x32_bf16(af, bf, acc[nt], 0, 0, 0);
        }
    }
#pragma unroll
    for (int nt = 0; nt < 4; ++nt) {
#pragma unroll
        for (int r = 0; r < 4; ++r) {
            int m = m0 + wave * 16 + quad * 4 + r;
            int col = n0 + nt * 16 + l16;
            long orow = (long)(m >> 9) * 513 + (m & 511) + 1;
            out_h[orow * HH + col] = acc[nt][r] + b_ih[col];
        }
    }
}

// ---------------------------------------------------------------------------
// Kernel B: sequential recurrence. grid 256 (1 block/batch), block 256 (4 waves).
// Thread (g = tid>>2, q = tid&3): outputs j = 4g..4g+3, k-quarter [64q, 64q+64).
// Weights 4x64 fp16 in regs (128 VGPRs). h fp16 in LDS, double-buffered,
// k-slices padded to 72 fp16 (disjoint bank groups per q). Per step:
// 8 ds_read_b128 + 128 v_dot2 + quad-DPP butterfly + 1 LDS-only barrier.
// U prefetch depth 2, floats across barriers (no vmcnt drain per step).
// Reads U from out_h row t+1 (written by gemm_u), overwrites it with h.
// ---------------------------------------------------------------------------
__global__ __launch_bounds__(256) void rnn_seq(
        const float* __restrict__ x0, const float* __restrict__ h0,
        const float* __restrict__ W_ih,
        float* __restrict__ out_x, float* __restrict__ out_h) {
    __shared__ __align__(16) _Float16 hsh[2][4][72];
    const int b = blockIdx.x;
    const int tid = threadIdx.x;
    const int g = tid >> 2;        // j-group 0..63
    const int q = tid & 3;         // k-quarter
    const int jm = (g << 2) + q;   // this lane's own output index (== tid)

    // weights W_h[4g+jp][64q + kk] -> w[jp][kk/2] as half2
    half2_t w[4][32];
    {
        const float* base = W_ih + 128 + 64 * q;
#pragma unroll
        for (int jp = 0; jp < 4; ++jp) {
            const float* wr = base + (long)(4 * g + jp) * 384;
#pragma unroll
            for (int i = 0; i < 16; ++i) {
                float4 v = *(const float4*)(wr + 4 * i);
                w[jp][2 * i]     = (half2_t){(_Float16)v.x, (_Float16)v.y};
                w[jp][2 * i + 1] = (half2_t){(_Float16)v.z, (_Float16)v.w};
            }
        }
    }

    float* hrow = out_h + (long)b * 513 * HH;
    // init: h0 -> LDS buf0 + global row 0; x0 -> x row 0; prefetch U rows 1,2
    {
        float hv = h0[(long)b * HH + jm];
        hrow[jm] = hv;
        hsh[0][jm >> 6][jm & 63] = (_Float16)hv;
    }
    if (tid < DOUT) out_x[(long)b * 513 * DOUT + tid] = x0[(long)b * DOUT + tid];
    float ucur = hrow[HH + jm];          // U row 1
    float unxt = hrow[2 * HH + jm];      // U row 2
    float* stp = hrow + HH + jm;         // store ptr: h row t+1
    const float* ldp = hrow + 3 * (long)HH + jm;  // load ptr: U row t+3
    __syncthreads();

    int cur = 0;
    for (int t = 0; t < TT; ++t) {
        const _Float16* hs = &hsh[cur][q][0];
        float a0 = 0.f, a1 = 0.f, a2 = 0.f, a3 = 0.f;
#pragma unroll
        for (int c = 0; c < 8; ++c) {
            half8_t hv = *(const half8_t*)(hs + 8 * c);
            half2_t p0 = {hv[0], hv[1]}, p1 = {hv[2], hv[3]};
            half2_t p2 = {hv[4], hv[5]}, p3 = {hv[6], hv[7]};
            a0 = fdot2f(p0, w[0][4 * c + 0], a0);
            a0 = fdot2f(p1, w[0][4 * c + 1], a0);
            a0 = fdot2f(p2, w[0][4 * c + 2], a0);
            a0 = fdot2f(p3, w[0][4 * c + 3], a0);
            a1 = fdot2f(p0, w[1][4 * c + 0], a1);
            a1 = fdot2f(p1, w[1][4 * c + 1], a1);
            a1 = fdot2f(p2, w[1][4 * c + 2], a1);
            a1 = fdot2f(p3, w[1][4 * c + 3], a1);
            a2 = fdot2f(p0, w[2][4 * c + 0], a2);
            a2 = fdot2f(p1, w[2][4 * c + 1], a2);
            a2 = fdot2f(p2, w[2][4 * c + 2], a2);
            a2 = fdot2f(p3, w[2][4 * c + 3], a2);
            a3 = fdot2f(p0, w[3][4 * c + 0], a3);
            a3 = fdot2f(p1, w[3][4 * c + 1], a3);
            a3 = fdot2f(p2, w[3][4 * c + 2], a3);
            a3 = fdot2f(p3, w[3][4 * c + 3], a3);
        }
        // quad butterfly: every lane gets full-k sums for all 4 j's of its group
        a0 = quad_bfly_add(a0);
        a1 = quad_bfly_add(a1);
        a2 = quad_bfly_add(a2);
        a3 = quad_bfly_add(a3);
        float s = (q == 0) ? a0 : (q == 1) ? a1 : (q == 2) ? a2 : a3;
        float tot = s + ucur;                         // ucur = U_t[jm] (has b_ih)
        float hn = tot >= 0.f ? tot : 0.01f * tot;    // LeakyReLU(0.01)
        int nxt = cur ^ 1;
        hsh[nxt][jm >> 6][jm & 63] = (_Float16)hn;    // contiguous b16 per wave
        stp[0] = hn;                                  // coalesced dword store, row t+1
        stp += HH;
        ucur = unxt;
        if (t < TT - 2) unxt = *ldp;                  // prefetch U row t+3 (depth 2)
        ldp += HH;
        block_sync_lds();                             // LDS-only wait; vmem floats
        cur = nxt;
    }
}

// ---------------------------------------------------------------------------
// Kernel C: x[b,t,:] = h[b,t,:] @ W_ho^T + b_ho, t=1..512.
// Full-K (256) staging, ONE barrier. grid 2048, block 256. Tile M64 x N64.
// ---------------------------------------------------------------------------
#define SX 264  // LDS row stride (shorts) for K=256: 528 B, 16-aligned
__global__ __launch_bounds__(256) void gemm_x(
        const float* __restrict__ out_h, const float* __restrict__ W_ho,
        const float* __restrict__ b_ho, float* __restrict__ out_x) {
    __shared__ __align__(16) short lA[64 * SX];
    __shared__ __align__(16) short lB[64 * SX];
    const int tid = threadIdx.x;
    const int wave = tid >> 6, lane = tid & 63;
    const int quad = lane >> 4, l16 = lane & 15;
    const int m0 = blockIdx.x * 64;
    const int bb = m0 >> 9, t0 = m0 & 511;
    const float* hsrc = out_h + ((long)bb * 513 + 1 + t0) * HH;
    float* xdst = out_x + ((long)bb * 513 + 1 + t0) * DOUT;
    const int sm = tid >> 2, skg = tid & 3;
    const int sn = tid & 63, bkg = tid >> 6;

#pragma unroll
    for (int ph = 0; ph < 2; ++ph) {   // two phases of 4 k-chunks to cap regs
        float4 a4[8], b4[8];
#pragma unroll
        for (int c = 0; c < 4; ++c) {
            int k0 = ph * 128 + c * 32;
            const float4* ap = (const float4*)(hsrc + (long)sm * HH + k0 + skg * 8);
            a4[2 * c] = ap[0]; a4[2 * c + 1] = ap[1];
            const float4* bp = (const float4*)(W_ho + (long)sn * HH + k0 + bkg * 8);
            b4[2 * c] = bp[0]; b4[2 * c + 1] = bp[1];
        }
#pragma unroll
        for (int c = 0; c < 4; ++c) {
            int k0 = ph * 128 + c * 32;
            bf16x8 av, bv;
            float4 x0 = a4[2 * c], x1 = a4[2 * c + 1];
            av[0] = f2bf(x0.x); av[1] = f2bf(x0.y); av[2] = f2bf(x0.z); av[3] = f2bf(x0.w);
            av[4] = f2bf(x1.x); av[5] = f2bf(x1.y); av[6] = f2bf(x1.z); av[7] = f2bf(x1.w);
            float4 y0 = b4[2 * c], y1 = b4[2 * c + 1];
            bv[0] = f2bf(y0.x); bv[1] = f2bf(y0.y); bv[2] = f2bf(y0.z); bv[3] = f2bf(y0.w);
            bv[4] = f2bf(y1.x); bv[5] = f2bf(y1.y); bv[6] = f2bf(y1.z); bv[7] = f2bf(y1.w);
            *(bf16x8*)&lA[sm * SX + k0 + skg * 8] = av;
            *(bf16x8*)&lB[sn * SX + k0 + bkg * 8] = bv;
        }
    }
    __syncthreads();

    f32x4 acc[4];
#pragma unroll
    for (int i = 0; i < 4; i++) acc[i] = (f32x4){0.f, 0.f, 0.f, 0.f};
#pragma unroll
    for (int c = 0; c < 8; ++c) {
        bf16x8 af = *(const bf16x8*)&lA[(wave * 16 + l16) * SX + c * 32 + quad * 8];
#pragma unroll
        for (int nt = 0; nt < 4; ++nt) {
            bf16x8 bf = *(const bf16x8*)&lB[(nt * 16 + l16) * SX + c * 32 + quad * 8];
            acc[nt] = __builtin_amdgcn_mfma_f32_16x16x32_bf16(af, bf, acc[nt], 0, 0, 0);
        }
    }
#pragma unroll
    for (int nt = 0; nt < 4; ++nt) {
#pragma unroll
        for (int r = 0; r < 4; ++r) {
            int mr = wave * 16 + quad * 4 + r;
            int col = nt * 16 + l16;
            xdst[(long)mr * DOUT + col] = acc[nt][r] + b_ho[col];
        }
    }
}

extern "C" void kernel_launch(void* const* d_in, const int* in_sizes, int n_in,
                              void* d_out, int out_size, void* d_ws, size_t ws_size,
                              hipStream_t stream) {
    const float* inp  = (const float*)d_in[0];
    const float* x0   = (const float*)d_in[1];
    const float* h0   = (const float*)d_in[2];
    const float* W_ih = (const float*)d_in[3];
    const float* b_ih = (const float*)d_in[4];
    const float* W_ho = (const float*)d_in[5];
    const float* b_ho = (const float*)d_in[6];
    float* out_x = (float*)d_out;
    float* out_h = out_x + X_ELEMS;

    gemm_u<<<dim3(2048, 4), 256, 0, stream>>>(inp, W_ih, b_ih, out_h);
    rnn_seq<<<dim3(256), 256, 0, stream>>>(x0, h0, W_ih, out_x, out_h);
    gemm_x<<<dim3(2048), 256, 0, stream>>>(out_h, W_ho, b_ho, out_x);
}

// Round 2
// 584.010 us; speedup vs baseline: 1.0563x; 1.0563x over previous
//
#include <hip/hip_runtime.h>

// Problem constants
#define BB 256
#define TT 512
#define DIN 128
#define HH 256
#define DOUT 64
#define X_ELEMS ((long)BB * 513 * DOUT)

typedef _Float16 half2_t __attribute__((ext_vector_type(2)));
typedef _Float16 half8_t __attribute__((ext_vector_type(8)));

static __device__ inline float fdot2f(half2_t a, half2_t b, float c) {
#if __has_builtin(__builtin_amdgcn_fdot2)
    return __builtin_amdgcn_fdot2(a, b, c, false);
#else
    return c + (float)a[0] * (float)b[0] + (float)a[1] * (float)b[1];
#endif
}

// butterfly-add across a lane quad via DPP quad_perm (XOR1 then XOR2).
// All 4 lanes of the quad end up with the full 4-lane sum. Pure VALU.
static __device__ inline float quad_bfly_add(float x) {
    int t = __builtin_amdgcn_mov_dpp(__float_as_int(x), 0xB1, 0xF, 0xF, true); // [1,0,3,2]
    x += __int_as_float(t);
    t = __builtin_amdgcn_mov_dpp(__float_as_int(x), 0x4E, 0xF, 0xF, true);     // [2,3,0,1]
    x += __int_as_float(t);
    return x;
}

// ---------------------------------------------------------------------------
// Fully fused RNN: one kernel does U = inp@W_u^T (on the fly, from LDS-staged
// inp rows), the h recurrence, AND x = h@W_ho^T. No U buffer, no separate
// GEMM kernels. grid 256 (1 block/batch/CU), block 256 (4 waves).
//
// Thread (g = tid>>2, q = tid&3): outputs j = 4g..4g+3.
//   h-dots:  k-quarter of HH  = [64q, 64q+64)   -> 128 dot2
//   U-dots:  k-quarter of DIN = [32q, 32q+32)   -> 64 dot2 (summed into same acc)
//   x-dots:  output g, k-quarter [64q, 64q+64)  -> 32 dot2 (after barrier,
//            from h(t+1) regs that are carried into the next iteration's h-dots)
// Weights fp16 in VGPRs: wh 128 + wu 64 + wo 32 = 224 VGPRs.
// inp rows staged in LDS fp16, double-buffered, prefetch depth 2.
// Per step: 4+8 ds_read_b128, ~224 dot2, 5 quad butterflies, 1 __syncthreads.
// Only per-step globals: h store (1 dword/thread), x store (1 dword/4 threads),
// inp prefetch (1 float2, wave 0 only, issued at loop top).
// ---------------------------------------------------------------------------
__global__ __launch_bounds__(256, 1) void rnn_fused(
        const float* __restrict__ inp, const float* __restrict__ x0,
        const float* __restrict__ h0, const float* __restrict__ W_ih,
        const float* __restrict__ b_ih, const float* __restrict__ W_ho,
        const float* __restrict__ b_ho,
        float* __restrict__ out_x, float* __restrict__ out_h) {
    __shared__ __align__(16) _Float16 hsh[2][4][72];   // h, k-slices padded to 72
    __shared__ __align__(16) _Float16 ibuf[2][DIN];    // staged inp rows (fp16)
    const int b = blockIdx.x;
    const int tid = threadIdx.x;
    const int g = tid >> 2, q = tid & 3;
    const int jm = tid;

    // ---- weight preload (fp16 in VGPRs) ----
    half2_t wh[4][32];  // W_ih rows 4g+jp, cols [128+64q, 128+64q+64)
    half2_t wu[4][16];  // W_ih rows 4g+jp, cols [32q, 32q+32)
    half2_t wo[32];     // W_ho row g,      cols [64q, 64q+64)
#pragma unroll
    for (int jp = 0; jp < 4; ++jp) {
        const float* wr = W_ih + (long)(4 * g + jp) * 384;
#pragma unroll
        for (int i = 0; i < 16; ++i) {
            float4 v = *(const float4*)(wr + 128 + 64 * q + 4 * i);
            wh[jp][2 * i]     = (half2_t){(_Float16)v.x, (_Float16)v.y};
            wh[jp][2 * i + 1] = (half2_t){(_Float16)v.z, (_Float16)v.w};
        }
#pragma unroll
        for (int i = 0; i < 8; ++i) {
            float4 v = *(const float4*)(wr + 32 * q + 4 * i);
            wu[jp][2 * i]     = (half2_t){(_Float16)v.x, (_Float16)v.y};
            wu[jp][2 * i + 1] = (half2_t){(_Float16)v.z, (_Float16)v.w};
        }
    }
#pragma unroll
    for (int i = 0; i < 16; ++i) {
        float4 v = *(const float4*)(W_ho + (long)g * HH + 64 * q + 4 * i);
        wo[2 * i]     = (half2_t){(_Float16)v.x, (_Float16)v.y};
        wo[2 * i + 1] = (half2_t){(_Float16)v.z, (_Float16)v.w};
    }
    const float bih_r = b_ih[jm];
    const float bho_r = b_ho[g];

    float* hrow = out_h + (long)b * 513 * HH;
    float* xrow = out_x + (long)b * 513 * DOUT;
    const float* irow = inp + (long)b * TT * DIN;

    // ---- init: h0 -> LDS buf0 + global row 0; x0 -> x row 0 ----
    {
        float hv0 = h0[(long)b * HH + jm];
        hrow[jm] = hv0;
        hsh[0][tid >> 6][tid & 63] = (_Float16)hv0;
    }
    if (tid < DOUT) xrow[tid] = x0[(long)b * DOUT + tid];
    // stage inp row 0 into ibuf[0]; prefetch row 1 into regs (64 lanes x float2)
    float2 ipf = {0.f, 0.f};
    if (tid < 64) {
        float2 v = *(const float2*)(irow + 2 * tid);
        *(half2_t*)&ibuf[0][2 * tid] = (half2_t){(_Float16)v.x, (_Float16)v.y};
        ipf = *(const float2*)(irow + DIN + 2 * tid);
    }
    __syncthreads();

    // initial h(0) slice into carried regs
    half8_t hv[8];
    {
        const _Float16* hs = &hsh[0][q][0];
#pragma unroll
        for (int c = 0; c < 8; ++c) hv[c] = *(const half8_t*)(hs + 8 * c);
    }

    const float* ipsrc = irow + 2 * DIN + 2 * tid;  // inp row t+2 (lanes < 64)
    float* hst = hrow + HH + jm;                    // h store: row t+1
    float* xst = xrow + DOUT + g;                   // x store: row t+1 (q==0)
    int cur = 0;
    for (int t = 0; t < TT; ++t) {
        // (1) early global prefetch: inp row t+2 (floats across whole step)
        float2 ipn = {0.f, 0.f};
        if (tid < 64 && t < TT - 2) ipn = *(const float2*)ipsrc;
        ipsrc += DIN;

        // (2) U ds reads (broadcast within wave, 4 x b128)
        const _Float16* ib = &ibuf[t & 1][q * 32];
        half8_t uv0 = *(const half8_t*)(ib);
        half8_t uv1 = *(const half8_t*)(ib + 8);
        half8_t uv2 = *(const half8_t*)(ib + 16);
        half8_t uv3 = *(const half8_t*)(ib + 24);

        float a0 = 0.f, a1 = 0.f, a2 = 0.f, a3 = 0.f;
        // (3) h-dots from carried regs (covers the LDS latency of uv reads)
#pragma unroll
        for (int c = 0; c < 8; ++c) {
            half8_t hvv = hv[c];
            half2_t p0 = {hvv[0], hvv[1]}, p1 = {hvv[2], hvv[3]};
            half2_t p2 = {hvv[4], hvv[5]}, p3 = {hvv[6], hvv[7]};
            a0 = fdot2f(p0, wh[0][4 * c + 0], a0);
            a0 = fdot2f(p1, wh[0][4 * c + 1], a0);
            a0 = fdot2f(p2, wh[0][4 * c + 2], a0);
            a0 = fdot2f(p3, wh[0][4 * c + 3], a0);
            a1 = fdot2f(p0, wh[1][4 * c + 0], a1);
            a1 = fdot2f(p1, wh[1][4 * c + 1], a1);
            a1 = fdot2f(p2, wh[1][4 * c + 2], a1);
            a1 = fdot2f(p3, wh[1][4 * c + 3], a1);
            a2 = fdot2f(p0, wh[2][4 * c + 0], a2);
            a2 = fdot2f(p1, wh[2][4 * c + 1], a2);
            a2 = fdot2f(p2, wh[2][4 * c + 2], a2);
            a2 = fdot2f(p3, wh[2][4 * c + 3], a2);
            a3 = fdot2f(p0, wh[3][4 * c + 0], a3);
            a3 = fdot2f(p1, wh[3][4 * c + 1], a3);
            a3 = fdot2f(p2, wh[3][4 * c + 2], a3);
            a3 = fdot2f(p3, wh[3][4 * c + 3], a3);
        }
        // (4) U-dots (same accumulators -> shared butterfly)
#define UDOT4(UV, c0)                                              \
        {                                                          \
            half2_t p0 = {UV[0], UV[1]}, p1 = {UV[2], UV[3]};      \
            half2_t p2 = {UV[4], UV[5]}, p3 = {UV[6], UV[7]};      \
            a0 = fdot2f(p0, wu[0][c0 + 0], a0);                    \
            a0 = fdot2f(p1, wu[0][c0 + 1], a0);                    \
            a0 = fdot2f(p2, wu[0][c0 + 2], a0);                    \
            a0 = fdot2f(p3, wu[0][c0 + 3], a0);                    \
            a1 = fdot2f(p0, wu[1][c0 + 0], a1);                    \
            a1 = fdot2f(p1, wu[1][c0 + 1], a1);                    \
            a1 = fdot2f(p2, wu[1][c0 + 2], a1);                    \
            a1 = fdot2f(p3, wu[1][c0 + 3], a1);                    \
            a2 = fdot2f(p0, wu[2][c0 + 0], a2);                    \
            a2 = fdot2f(p1, wu[2][c0 + 1], a2);                    \
            a2 = fdot2f(p2, wu[2][c0 + 2], a2);                    \
            a2 = fdot2f(p3, wu[2][c0 + 3], a2);                    \
            a3 = fdot2f(p0, wu[3][c0 + 0], a3);                    \
            a3 = fdot2f(p1, wu[3][c0 + 1], a3);                    \
            a3 = fdot2f(p2, wu[3][c0 + 2], a3);                    \
            a3 = fdot2f(p3, wu[3][c0 + 3], a3);                    \
        }
        UDOT4(uv0, 0)
        UDOT4(uv1, 4)
        UDOT4(uv2, 8)
        UDOT4(uv3, 12)
#undef UDOT4

        // (5) quad butterfly + activation
        a0 = quad_bfly_add(a0);
        a1 = quad_bfly_add(a1);
        a2 = quad_bfly_add(a2);
        a3 = quad_bfly_add(a3);
        float s = (q == 0) ? a0 : (q == 1) ? a1 : (q == 2) ? a2 : a3;
        float tot = s + bih_r;
        float hn = tot >= 0.f ? tot : 0.01f * tot;    // LeakyReLU(0.01)
        int nxt = cur ^ 1;
        hsh[nxt][tid >> 6][tid & 63] = (_Float16)hn;
        hst[0] = hn;                                  // coalesced dword store
        hst += HH;
        // (6) write staged inp row t+1 (loaded last iteration)
        if (tid < 64 && t < TT - 1)
            *(half2_t*)&ibuf[(t + 1) & 1][2 * tid] =
                (half2_t){(_Float16)ipf.x, (_Float16)ipf.y};
        ipf = ipn;
        __syncthreads();

        // (7) x-phase: read h(t+1) (carried into next iter's h-dots),
        //     compute x(t+1) = h(t+1)@W_ho^T + b_ho
        const _Float16* hs = &hsh[nxt][q][0];
#pragma unroll
        for (int c = 0; c < 8; ++c) hv[c] = *(const half8_t*)(hs + 8 * c);
        float ax = 0.f;
#pragma unroll
        for (int c = 0; c < 8; ++c) {
            half8_t hvv = hv[c];
            ax = fdot2f((half2_t){hvv[0], hvv[1]}, wo[4 * c + 0], ax);
            ax = fdot2f((half2_t){hvv[2], hvv[3]}, wo[4 * c + 1], ax);
            ax = fdot2f((half2_t){hvv[4], hvv[5]}, wo[4 * c + 2], ax);
            ax = fdot2f((half2_t){hvv[6], hvv[7]}, wo[4 * c + 3], ax);
        }
        ax = quad_bfly_add(ax);
        if (q == 0) xst[0] = ax + bho_r;
        xst += DOUT;
        cur = nxt;
    }
}

extern "C" void kernel_launch(void* const* d_in, const int* in_sizes, int n_in,
                              void* d_out, int out_size, void* d_ws, size_t ws_size,
                              hipStream_t stream) {
    const float* inp  = (const float*)d_in[0];
    const float* x0   = (const float*)d_in[1];
    const float* h0   = (const float*)d_in[2];
    const float* W_ih = (const float*)d_in[3];
    const float* b_ih = (const float*)d_in[4];
    const float* W_ho = (const float*)d_in[5];
    const float* b_ho = (const float*)d_in[6];
    float* out_x = (float*)d_out;
    float* out_h = out_x + X_ELEMS;

    rnn_fused<<<dim3(256), 256, 0, stream>>>(inp, x0, h0, W_ih, b_ih, W_ho, b_ho,
                                             out_x, out_h);
}

// Round 3
// 582.289 us; speedup vs baseline: 1.0594x; 1.0030x over previous
//
#include <hip/hip_runtime.h>

// Problem constants
#define BB 256
#define TT 512
#define DIN 128
#define HH 256
#define DOUT 64
#define X_ELEMS ((long)BB * 513 * DOUT)

typedef _Float16 half2_t __attribute__((ext_vector_type(2)));
typedef _Float16 half8_t __attribute__((ext_vector_type(8)));

static __device__ inline float fdot2f(half2_t a, half2_t b, float c) {
#if __has_builtin(__builtin_amdgcn_fdot2)
    return __builtin_amdgcn_fdot2(a, b, c, false);
#else
    return c + (float)a[0] * (float)b[0] + (float)a[1] * (float)b[1];
#endif
}

// butterfly-add across a lane quad via DPP quad_perm (XOR1 then XOR2).
// All 4 lanes of the quad end up with the full 4-lane sum. Pure VALU.
static __device__ inline float quad_bfly_add(float x) {
    int t = __builtin_amdgcn_mov_dpp(__float_as_int(x), 0xB1, 0xF, 0xF, true); // [1,0,3,2]
    x += __int_as_float(t);
    t = __builtin_amdgcn_mov_dpp(__float_as_int(x), 0x4E, 0xF, 0xF, true);     // [2,3,0,1]
    x += __int_as_float(t);
    return x;
}

// XOR-4 exchange (across the two quads of an octet) via static ds_swizzle.
static __device__ inline float xor4_add(float x) {
    int t = __builtin_amdgcn_ds_swizzle(__float_as_int(x), 0x101F); // xor lane^4
    return x + __int_as_float(t);
}

// ---------------------------------------------------------------------------
// Fully fused RNN, 512 threads/block (8 waves -> 2 waves/SIMD), k-split 8.
// grid 256 (1 block/batch/CU).
// Thread (g8 = tid>>3, q8 = tid&7):
//   h-dots: 4 outputs j=4*g8..+3, k-chunk [32*q8, +32)  -> 64 dot2
//   U-dots: same 4 outputs,       k-chunk [16*q8, +16)  -> 32 dot2
//   x-dots: output g8,            k-chunk [32*q8, +32)  -> 16 dot2
// Weights fp16 in VGPRs: wh 64 + wu 32 + wo 16 = 112 (vs 224 at 256thr ->
// no AGPR shuffling). Reduce: 2-stage DPP quad butterfly, then select own
// accumulator, then ONE ds_swizzle XOR-4 -> full 8-lane sum.
// h in LDS fp16, 8 chunks of 32 @ stride 40 halves (bases on disjoint bank
// groups), double-buffered. inp row staged in LDS fp16, double-buffered,
// prefetch depth 2. Global h/x stores DEFERRED one step (in regs) so the
// __syncthreads vmcnt(0) drain waits on ~650-cycle-old ops (complete).
// ---------------------------------------------------------------------------
__global__ __launch_bounds__(512, 2) void rnn_fused(
        const float* __restrict__ inp, const float* __restrict__ x0,
        const float* __restrict__ h0, const float* __restrict__ W_ih,
        const float* __restrict__ b_ih, const float* __restrict__ W_ho,
        const float* __restrict__ b_ho,
        float* __restrict__ out_x, float* __restrict__ out_h) {
    __shared__ __align__(16) _Float16 hsh[2][8][40];   // h chunks, stride 40
    __shared__ __align__(16) _Float16 ibuf[2][DIN];    // staged inp rows
    const int b = blockIdx.x;
    const int tid = threadIdx.x;
    const int g8 = tid >> 3, q8 = tid & 7, qs = q8 & 3;
    const bool hwv = (q8 < 4);     // h writer (owns j_own)
    const bool xwv = (q8 == 4);    // x writer (owns x[g8])
    const bool iwv = (tid < 64);   // inp stager

    // ---- weight preload (fp16 in VGPRs) ----
    half2_t wh[4][16];  // W_ih[4g8+jp][128 + 32q8 + 2i]
    half2_t wu[4][8];   // W_ih[4g8+jp][16q8 + 2i]
    half2_t wo[16];     // W_ho[g8][32q8 + 2i]
#pragma unroll
    for (int jp = 0; jp < 4; ++jp) {
        const float* wr = W_ih + (long)(4 * g8 + jp) * 384;
#pragma unroll
        for (int i = 0; i < 8; ++i) {
            float4 v = *(const float4*)(wr + 128 + 32 * q8 + 4 * i);
            wh[jp][2 * i]     = (half2_t){(_Float16)v.x, (_Float16)v.y};
            wh[jp][2 * i + 1] = (half2_t){(_Float16)v.z, (_Float16)v.w};
        }
#pragma unroll
        for (int i = 0; i < 4; ++i) {
            float4 v = *(const float4*)(wr + 16 * q8 + 4 * i);
            wu[jp][2 * i]     = (half2_t){(_Float16)v.x, (_Float16)v.y};
            wu[jp][2 * i + 1] = (half2_t){(_Float16)v.z, (_Float16)v.w};
        }
    }
#pragma unroll
    for (int i = 0; i < 8; ++i) {
        float4 v = *(const float4*)(W_ho + (long)g8 * HH + 32 * q8 + 4 * i);
        wo[2 * i]     = (half2_t){(_Float16)v.x, (_Float16)v.y};
        wo[2 * i + 1] = (half2_t){(_Float16)v.z, (_Float16)v.w};
    }
    const int j_own = 4 * g8 + qs;
    const float bih = b_ih[j_own];
    const float bho = b_ho[g8];

    // LDS addresses (precomputed, static per buffer)
    _Float16* hsw0 = &hsh[0][j_own >> 5][j_own & 31];
    _Float16* hsw1 = &hsh[1][j_own >> 5][j_own & 31];
    const _Float16* hsr0 = &hsh[0][q8][0];
    const _Float16* hsr1 = &hsh[1][q8][0];

    float* hrow = out_h + (long)b * 513 * HH;
    float* xrow = out_x + (long)b * 513 * DOUT;
    const float* irow = inp + (long)b * TT * DIN;

    // ---- init: h0 -> LDS buf0 + deferred reg; x0 -> deferred reg ----
    float hprev = 0.f, xprev = 0.f;
    if (hwv) {
        hprev = h0[(long)b * HH + j_own];
        *hsw0 = (_Float16)hprev;
    }
    if (xwv) xprev = x0[(long)b * DOUT + g8];
    float2 ipf = {0.f, 0.f};
    if (iwv) {
        float2 v = *(const float2*)(irow + 2 * tid);
        *(half2_t*)&ibuf[0][2 * tid] = (half2_t){(_Float16)v.x, (_Float16)v.y};
        ipf = *(const float2*)(irow + DIN + 2 * tid);   // row 1
    }
    __syncthreads();

    // initial h(0) chunk into carried regs
    half8_t hv0 = *(const half8_t*)(hsr0);
    half8_t hv1 = *(const half8_t*)(hsr0 + 8);
    half8_t hv2 = *(const half8_t*)(hsr0 + 16);
    half8_t hv3 = *(const half8_t*)(hsr0 + 24);

    const float* ipsrc = irow + 2 * DIN + 2 * tid;  // row t+2 (lanes < 64)
    float* hst = hrow + j_own;                      // deferred store: row t
    float* xst = xrow + g8;

#define HDOT(HV, C)                                                         \
    {                                                                       \
        half2_t p0 = {HV[0], HV[1]}, p1 = {HV[2], HV[3]};                   \
        half2_t p2 = {HV[4], HV[5]}, p3 = {HV[6], HV[7]};                   \
        a0 = fdot2f(p0, wh[0][4 * (C) + 0], a0);                            \
        a0 = fdot2f(p1, wh[0][4 * (C) + 1], a0);                            \
        a0 = fdot2f(p2, wh[0][4 * (C) + 2], a0);                            \
        a0 = fdot2f(p3, wh[0][4 * (C) + 3], a0);                            \
        a1 = fdot2f(p0, wh[1][4 * (C) + 0], a1);                            \
        a1 = fdot2f(p1, wh[1][4 * (C) + 1], a1);                            \
        a1 = fdot2f(p2, wh[1][4 * (C) + 2], a1);                            \
        a1 = fdot2f(p3, wh[1][4 * (C) + 3], a1);                            \
        a2 = fdot2f(p0, wh[2][4 * (C) + 0], a2);                            \
        a2 = fdot2f(p1, wh[2][4 * (C) + 1], a2);                            \
        a2 = fdot2f(p2, wh[2][4 * (C) + 2], a2);                            \
        a2 = fdot2f(p3, wh[2][4 * (C) + 3], a2);                            \
        a3 = fdot2f(p0, wh[3][4 * (C) + 0], a3);                            \
        a3 = fdot2f(p1, wh[3][4 * (C) + 1], a3);                            \
        a3 = fdot2f(p2, wh[3][4 * (C) + 2], a3);                            \
        a3 = fdot2f(p3, wh[3][4 * (C) + 3], a3);                            \
    }

#define UDOT(UV, C)                                                         \
    {                                                                       \
        half2_t p0 = {UV[0], UV[1]}, p1 = {UV[2], UV[3]};                   \
        half2_t p2 = {UV[4], UV[5]}, p3 = {UV[6], UV[7]};                   \
        a0 = fdot2f(p0, wu[0][(C) + 0], a0);                                \
        a0 = fdot2f(p1, wu[0][(C) + 1], a0);                                \
        a0 = fdot2f(p2, wu[0][(C) + 2], a0);                                \
        a0 = fdot2f(p3, wu[0][(C) + 3], a0);                                \
        a1 = fdot2f(p0, wu[1][(C) + 0], a1);                                \
        a1 = fdot2f(p1, wu[1][(C) + 1], a1);                                \
        a1 = fdot2f(p2, wu[1][(C) + 2], a1);                                \
        a1 = fdot2f(p3, wu[1][(C) + 3], a1);                                \
        a2 = fdot2f(p0, wu[2][(C) + 0], a2);                                \
        a2 = fdot2f(p1, wu[2][(C) + 1], a2);                                \
        a2 = fdot2f(p2, wu[2][(C) + 2], a2);                                \
        a2 = fdot2f(p3, wu[2][(C) + 3], a2);                                \
        a3 = fdot2f(p0, wu[3][(C) + 0], a3);                                \
        a3 = fdot2f(p1, wu[3][(C) + 1], a3);                                \
        a3 = fdot2f(p2, wu[3][(C) + 2], a3);                                \
        a3 = fdot2f(p3, wu[3][(C) + 3], a3);                                \
    }

#define XDOT(HV, C)                                                         \
    {                                                                       \
        ax = fdot2f((half2_t){HV[0], HV[1]}, wo[4 * (C) + 0], ax);          \
        ax = fdot2f((half2_t){HV[2], HV[3]}, wo[4 * (C) + 1], ax);          \
        ax = fdot2f((half2_t){HV[4], HV[5]}, wo[4 * (C) + 2], ax);          \
        ax = fdot2f((half2_t){HV[6], HV[7]}, wo[4 * (C) + 3], ax);          \
    }

// One recurrence step. T = step index, PC = current parity buf, PN = next.
// HRD = LDS read base for h(T+1), HWD = LDS write addr for h(T+1).
#define STEP(T, PC, PN, HRD, HWD)                                           \
    {                                                                       \
        /* deferred global stores from previous step (row T) */             \
        if (hwv) hst[0] = hprev;                                            \
        if (xwv) xst[0] = xprev;                                            \
        hst += HH; xst += DOUT;                                             \
        /* prefetch inp row T+2 (floats across the whole step) */           \
        float2 ipn = {0.f, 0.f};                                            \
        if (iwv && (T) + 2 < TT) ipn = *(const float2*)ipsrc;               \
        ipsrc += DIN;                                                       \
        /* U chunk from staged row T */                                     \
        const _Float16* ib = &ibuf[PC][16 * q8];                            \
        half8_t uv0 = *(const half8_t*)(ib);                                \
        half8_t uv1 = *(const half8_t*)(ib + 8);                            \
        float a0 = 0.f, a1 = 0.f, a2 = 0.f, a3 = 0.f;                       \
        HDOT(hv0, 0) HDOT(hv1, 1) HDOT(hv2, 2) HDOT(hv3, 3)                 \
        UDOT(uv0, 0) UDOT(uv1, 4)                                           \
        a0 = quad_bfly_add(a0);                                             \
        a1 = quad_bfly_add(a1);                                             \
        a2 = quad_bfly_add(a2);                                             \
        a3 = quad_bfly_add(a3);                                             \
        float sp = (qs == 0) ? a0 : (qs == 1) ? a1 : (qs == 2) ? a2 : a3;   \
        float s = xor4_add(sp);                                             \
        float tot = s + bih;                                                \
        float hn = tot >= 0.f ? tot : 0.01f * tot;                          \
        if (hwv) *(HWD) = (_Float16)hn;                                     \
        if (iwv) *(half2_t*)&ibuf[PN][2 * tid] =                            \
            (half2_t){(_Float16)ipf.x, (_Float16)ipf.y};                    \
        ipf = ipn;                                                          \
        hprev = hn;                                                         \
        __syncthreads();                                                    \
        /* read h(T+1) chunk: feeds x(T+1) now and h-dots next step */      \
        hv0 = *(const half8_t*)(HRD);                                       \
        hv1 = *(const half8_t*)(HRD + 8);                                   \
        hv2 = *(const half8_t*)(HRD + 16);                                  \
        hv3 = *(const half8_t*)(HRD + 24);                                  \
        float ax = 0.f;                                                     \
        XDOT(hv0, 0) XDOT(hv1, 1) XDOT(hv2, 2) XDOT(hv3, 3)                 \
        ax = quad_bfly_add(ax);                                             \
        ax = xor4_add(ax);                                                  \
        xprev = ax + bho;                                                   \
    }

    for (int t = 0; t < TT; t += 2) {
        STEP(t,     0, 1, hsr1, hsw1)
        STEP(t + 1, 1, 0, hsr0, hsw0)
    }
    // final deferred stores: row 512
    if (hwv) hst[0] = hprev;
    if (xwv) xst[0] = xprev;

#undef STEP
#undef HDOT
#undef UDOT
#undef XDOT
}

extern "C" void kernel_launch(void* const* d_in, const int* in_sizes, int n_in,
                              void* d_out, int out_size, void* d_ws, size_t ws_size,
                              hipStream_t stream) {
    const float* inp  = (const float*)d_in[0];
    const float* x0   = (const float*)d_in[1];
    const float* h0   = (const float*)d_in[2];
    const float* W_ih = (const float*)d_in[3];
    const float* b_ih = (const float*)d_in[4];
    const float* W_ho = (const float*)d_in[5];
    const float* b_ho = (const float*)d_in[6];
    float* out_x = (float*)d_out;
    float* out_h = out_x + X_ELEMS;

    rnn_fused<<<dim3(256), 512, 0, stream>>>(inp, x0, h0, W_ih, b_ih, W_ho, b_ho,
                                             out_x, out_h);
}